// Round 1
// baseline (276.480 us; speedup 1.0000x reference)
//
#include <hip/hip_runtime.h>

// ============================================================================
// ExtraAttention on MI355X (gfx950), bf16 MFMA pipeline.
// Stages: cvt(x,M) -> transpose_cvt(W_attn,W_mem,W_proj) -> GEMM QKV ->
//         GEMM EKV -> flash attention (no-max softmax) -> GEMM proj (fp32 out)
// Dims: B=4 S=1024 P=128 NX=1024 H=16 dh=64 T=1152
// ============================================================================

typedef __attribute__((ext_vector_type(8))) short bf16x8;
typedef __attribute__((ext_vector_type(4))) float f32x4;

#define MFMA16(a, b, c) __builtin_amdgcn_mfma_f32_16x16x32_bf16((a), (b), (c), 0, 0, 0)

static __device__ __forceinline__ unsigned short f2bf(float f) {
    union { float f; unsigned int u; } v; v.f = f;
    unsigned int u = v.u;
    return (unsigned short)((u + 0x7fffu + ((u >> 16) & 1u)) >> 16);  // RNE
}

// ---------------------------------------------------------------------------
// fp32 -> bf16, 4 elems/thread
__global__ void cvt_f32_bf16(const float* __restrict__ in, unsigned short* __restrict__ out, int n4) {
    int i = blockIdx.x * 256 + threadIdx.x;
    if (i >= n4) return;
    float4 v = ((const float4*)in)[i];
    ushort4 o;
    o.x = f2bf(v.x); o.y = f2bf(v.y); o.z = f2bf(v.z); o.w = f2bf(v.w);
    ((ushort4*)out)[i] = o;
}

// ---------------------------------------------------------------------------
// W [K][N] fp32 row-major -> Wt [N][K] bf16 row-major (32x32 LDS tiles)
__global__ void transpose_cvt(const float* __restrict__ W, unsigned short* __restrict__ Wt,
                              int K, int N) {
    __shared__ float tile[32][33];
    int n0 = blockIdx.x * 32, k0 = blockIdx.y * 32;
    int tx = threadIdx.x & 31, ty = threadIdx.x >> 5;  // 256 thr: ty 0..7
    #pragma unroll
    for (int r = ty; r < 32; r += 8) tile[r][tx] = W[(size_t)(k0 + r) * N + n0 + tx];
    __syncthreads();
    #pragma unroll
    for (int r = ty; r < 32; r += 8) Wt[(size_t)(n0 + r) * K + k0 + tx] = f2bf(tile[tx][r]);
}

// ---------------------------------------------------------------------------
// C[M][N] = A[M][K](bf16) x Bt[N][K](bf16)^T + bias[N]
// 128x128 block tile, BK=32, 4 waves (each 64x64 = 4x4 MFMA 16x16x32 tiles).
// LDS rows padded to 40 elems (80 B) to spread banks.
template <int STORE_BF16>
__global__ __launch_bounds__(256) void gemm_bt(const unsigned short* __restrict__ A,
                                               const unsigned short* __restrict__ Bt,
                                               const float* __restrict__ bias,
                                               void* __restrict__ C, int M, int N, int K) {
    __shared__ unsigned short As[128 * 40];
    __shared__ unsigned short Bs[128 * 40];
    const int tid = threadIdx.x;
    const int lane = tid & 63, wave = tid >> 6;
    const int quad = lane >> 4, l16 = lane & 15;
    const int wm = (wave & 1) * 64, wn = (wave >> 1) * 64;
    const int bm = blockIdx.x, bn = blockIdx.y;
    const int srow = tid >> 1, scol = (tid & 1) * 16;  // 2 threads/row, 16 k each
    const unsigned short* Ag = A + (size_t)(bm * 128 + srow) * K + scol;
    const unsigned short* Bg = Bt + (size_t)(bn * 128 + srow) * K + scol;

    f32x4 acc[4][4] = {};
    for (int k0 = 0; k0 < K; k0 += 32) {
        bf16x8 a0 = *(const bf16x8*)(Ag + k0);
        bf16x8 a1 = *(const bf16x8*)(Ag + k0 + 8);
        bf16x8 b0 = *(const bf16x8*)(Bg + k0);
        bf16x8 b1 = *(const bf16x8*)(Bg + k0 + 8);
        __syncthreads();  // protect previous iteration's LDS reads
        *(bf16x8*)&As[srow * 40 + scol] = a0;
        *(bf16x8*)&As[srow * 40 + scol + 8] = a1;
        *(bf16x8*)&Bs[srow * 40 + scol] = b0;
        *(bf16x8*)&Bs[srow * 40 + scol + 8] = b1;
        __syncthreads();
        bf16x8 af[4], bf[4];
        #pragma unroll
        for (int i = 0; i < 4; i++) af[i] = *(const bf16x8*)&As[(wm + i * 16 + l16) * 40 + quad * 8];
        #pragma unroll
        for (int j = 0; j < 4; j++) bf[j] = *(const bf16x8*)&Bs[(wn + j * 16 + l16) * 40 + quad * 8];
        #pragma unroll
        for (int i = 0; i < 4; i++)
            #pragma unroll
            for (int j = 0; j < 4; j++)
                acc[i][j] = MFMA16(af[i], bf[j], acc[i][j]);
    }
    // epilogue: D col = lane&15, row = quad*4 + reg (verified m89/m91)
    float bj[4];
    #pragma unroll
    for (int j = 0; j < 4; j++) bj[j] = bias[bn * 128 + wn + j * 16 + l16];
    #pragma unroll
    for (int i = 0; i < 4; i++) {
        const int row = bm * 128 + wm + i * 16 + quad * 4;
        #pragma unroll
        for (int j = 0; j < 4; j++) {
            const int col = bn * 128 + wn + j * 16 + l16;
            #pragma unroll
            for (int r = 0; r < 4; r++) {
                float v = acc[i][j][r] + bj[j];
                if (STORE_BF16)
                    ((unsigned short*)C)[(size_t)(row + r) * N + col] = f2bf(v);
                else
                    ((float*)C)[(size_t)(row + r) * N + col] = v;
            }
        }
    }
}

// ---------------------------------------------------------------------------
// Attention: one block = (b, h, 64 q-rows); wave w owns q-rows [qt*64+w*16, +16).
// K/V streamed in 32-t tiles through LDS (K as [t][d], V transposed [d][t]).
// Softmax without max-subtraction (scores bounded << 88): num/den accumulate.
__global__ __launch_bounds__(256) void attn_kernel(const unsigned short* __restrict__ QKV,
                                                   const unsigned short* __restrict__ EKV,
                                                   const float* __restrict__ Mmask,
                                                   const float* __restrict__ amask,
                                                   unsigned short* __restrict__ Aout) {
    __shared__ unsigned short Ks[32 * 72];     // [t][d], row stride 72
    __shared__ unsigned short Vs[64 * 40];     // [d][t], row stride 40
    __shared__ unsigned short Ps[4][16 * 40];  // per-wave P tile [s][t], stride 40
    const int tid = threadIdx.x;
    const int lane = tid & 63, wave = tid >> 6;
    const int quad = lane >> 4, l16 = lane & 15;
    const int blk = blockIdx.x;
    const int qt = blk & 15, h = (blk >> 4) & 15, b = blk >> 8;
    const int qrow = qt * 64 + wave * 16;  // global s base for this wave

    // Q fragments (A-operand: m = lane&15, k = quad*8+j; dh=64 -> 2 chunks)
    const unsigned short* qp = QKV + (size_t)(b * 1024 + qrow + l16) * 3072 + h * 64 + quad * 8;
    bf16x8 q0 = *(const bf16x8*)qp;
    bf16x8 q1 = *(const bf16x8*)(qp + 32);

    f32x4 o0 = {}, o1 = {}, o2 = {}, o3 = {};
    float den[4] = {0.f, 0.f, 0.f, 0.f};
    const int st_t = tid >> 3, st_d = (tid & 7) * 8;  // staging: 8 elems/thread

    for (int t0 = 0; t0 < 1152; t0 += 32) {
        const int tg = t0 + st_t;
        const unsigned short* kg;
        if (tg < 128) kg = EKV + (size_t)(b * 128 + tg) * 2048 + h * 64 + st_d;
        else          kg = QKV + (size_t)(b * 1024 + (tg - 128)) * 3072 + 1024 + h * 64 + st_d;
        bf16x8 kv = *(const bf16x8*)kg;
        bf16x8 vv = *(const bf16x8*)(kg + 1024);  // v is +NX after k in both layouts
        __syncthreads();
        *(bf16x8*)&Ks[st_t * 72 + st_d] = kv;
        #pragma unroll
        for (int j = 0; j < 8; j++) Vs[(st_d + j) * 40 + st_t] = (unsigned short)vv[j];
        __syncthreads();

        #pragma unroll
        for (int st = 0; st < 2; st++) {
            // B-operand = K^T: B[k=d][n=t] = K[t][d]; lane reads row (st*16+l16)
            bf16x8 kf0 = *(const bf16x8*)&Ks[(st * 16 + l16) * 72 + quad * 8];
            bf16x8 kf1 = *(const bf16x8*)&Ks[(st * 16 + l16) * 72 + 32 + quad * 8];
            f32x4 s = {};
            s = MFMA16(q0, kf0, s);
            s = MFMA16(q1, kf1, s);
            const int tgc = t0 + st * 16 + l16;  // this lane's key index (column)
            float addb;
            if (tgc < 128) addb = (Mmask[b * 128 + tgc] - 1.f) * 10000.f;
            else           addb = amask[b * 1024 + (tgc - 128)];
            #pragma unroll
            for (int r = 0; r < 4; r++) {
                const int srow_g = qrow + quad * 4 + r;
                float p = 0.f;
                if (tgc < 128 || (tgc - 128) <= srow_g)  // memory always visible; causal self
                    p = __expf(s[r] * 0.125f + addb);
                den[r] += p;
                Ps[wave][(quad * 4 + r) * 40 + st * 16 + l16] = f2bf(p);
            }
        }
        // P (C-layout) -> A-operand via per-wave LDS round trip
        bf16x8 pf = *(const bf16x8*)&Ps[wave][l16 * 40 + quad * 8];
        bf16x8 vf0 = *(const bf16x8*)&Vs[(0 * 16 + l16) * 40 + quad * 8];
        bf16x8 vf1 = *(const bf16x8*)&Vs[(1 * 16 + l16) * 40 + quad * 8];
        bf16x8 vf2 = *(const bf16x8*)&Vs[(2 * 16 + l16) * 40 + quad * 8];
        bf16x8 vf3 = *(const bf16x8*)&Vs[(3 * 16 + l16) * 40 + quad * 8];
        o0 = MFMA16(pf, vf0, o0);
        o1 = MFMA16(pf, vf1, o1);
        o2 = MFMA16(pf, vf2, o2);
        o3 = MFMA16(pf, vf3, o3);
    }

    // row-sum of den across the 16 lanes sharing a quad
    #pragma unroll
    for (int r = 0; r < 4; r++)
        #pragma unroll
        for (int m = 1; m < 16; m <<= 1)
            den[r] += __shfl_xor(den[r], m, 64);

    #pragma unroll
    for (int r = 0; r < 4; r++) {
        const float inv = 1.f / den[r];
        const size_t orow = (size_t)(b * 1024 + qrow + quad * 4 + r) * 1024 + h * 64;
        Aout[orow + 0 * 16 + l16] = f2bf(o0[r] * inv);
        Aout[orow + 1 * 16 + l16] = f2bf(o1[r] * inv);
        Aout[orow + 2 * 16 + l16] = f2bf(o2[r] * inv);
        Aout[orow + 3 * 16 + l16] = f2bf(o3[r] * inv);
    }
}

// ---------------------------------------------------------------------------
extern "C" void kernel_launch(void* const* d_in, const int* in_sizes, int n_in,
                              void* d_out, int out_size, void* d_ws, size_t ws_size,
                              hipStream_t stream) {
    const float* x      = (const float*)d_in[0];   // [4,1024,1024]
    const float* Mem    = (const float*)d_in[1];   // [4,128,1024]
    const float* Mmask  = (const float*)d_in[2];   // [4,128]
    const float* amask  = (const float*)d_in[3];   // [4,1,1,1024]
    const float* W_attn = (const float*)d_in[4];   // [1024,3072]
    const float* b_attn = (const float*)d_in[5];   // [3072]
    const float* W_mem  = (const float*)d_in[6];   // [1024,2048]
    const float* b_mem  = (const float*)d_in[7];   // [2048]
    const float* W_proj = (const float*)d_in[8];   // [1024,1024]
    const float* b_proj = (const float*)d_in[9];   // [1024]
    float* out = (float*)d_out;                    // [4,1024,1024] fp32

    char* ws = (char*)d_ws;
    unsigned short* x_bf = (unsigned short*)ws;  ws += (size_t)4096 * 1024 * 2;
    unsigned short* M_bf = (unsigned short*)ws;  ws += (size_t)512 * 1024 * 2;
    unsigned short* Wat  = (unsigned short*)ws;  ws += (size_t)3072 * 1024 * 2;
    unsigned short* Wmt  = (unsigned short*)ws;  ws += (size_t)2048 * 1024 * 2;
    unsigned short* Wpt  = (unsigned short*)ws;  ws += (size_t)1024 * 1024 * 2;
    unsigned short* QKV  = (unsigned short*)ws;  ws += (size_t)4096 * 3072 * 2;
    unsigned short* EKV  = (unsigned short*)ws;  ws += (size_t)512 * 2048 * 2;
    unsigned short* Abuf = (unsigned short*)ws;  ws += (size_t)4096 * 1024 * 2;
    // total ws use: ~57.7 MB

    cvt_f32_bf16<<<4096, 256, 0, stream>>>(x, x_bf, 4096 * 1024 / 4);
    cvt_f32_bf16<<<512, 256, 0, stream>>>(Mem, M_bf, 512 * 1024 / 4);
    transpose_cvt<<<dim3(96, 32), 256, 0, stream>>>(W_attn, Wat, 1024, 3072);
    transpose_cvt<<<dim3(64, 32), 256, 0, stream>>>(W_mem, Wmt, 1024, 2048);
    transpose_cvt<<<dim3(32, 32), 256, 0, stream>>>(W_proj, Wpt, 1024, 1024);

    gemm_bt<1><<<dim3(32, 24), 256, 0, stream>>>(x_bf, Wat, b_attn, QKV, 4096, 3072, 1024);
    gemm_bt<1><<<dim3(4, 16), 256, 0, stream>>>(M_bf, Wmt, b_mem, EKV, 512, 2048, 1024);

    attn_kernel<<<1024, 256, 0, stream>>>(QKV, EKV, Mmask, amask, Abuf);

    gemm_bt<0><<<dim3(32, 8), 256, 0, stream>>>(Abuf, Wpt, b_proj, out, 4096, 1024, 1024);
}